// Round 2
// baseline (248.804 us; speedup 1.0000x reference)
//
#include <hip/hip_runtime.h>
#include <hip/hip_bf16.h>
#include <stdint.h>

#define DIM 64
#define PH  64
#define TH  256
#define NN  512

typedef __attribute__((ext_vector_type(8))) short bf16x8;
typedef __attribute__((ext_vector_type(4))) float f32x4;

__device__ __forceinline__ short f2bf(float f) {
    union { float f; uint32_t u; } v; v.f = f;
    uint32_t r = v.u + 0x7fffu + ((v.u >> 16) & 1u);
    return (short)(r >> 16);
}
__device__ __forceinline__ float bf2f(short s) {
    union { uint32_t u; float f; } v; v.u = ((uint32_t)(uint16_t)s) << 16;
    return v.f;
}

// M[h][t] = sum_d pos_w2[h][d] * attn_w1[d][t], stored t-major: Mg[t*PH+h] (bf16)
// cb[t]   = attn_b1[t] + sum_d pos_b2[d] * attn_w1[d][t]
__global__ void prep_w(const float* __restrict__ pos_w2, const float* __restrict__ attn_w1,
                       const float* __restrict__ pos_b2, const float* __restrict__ attn_b1,
                       short* __restrict__ Mg, float* __restrict__ cbg) {
    int h = blockIdx.x, t = threadIdx.x;
    float m = 0.f;
    for (int d = 0; d < DIM; d++) m += pos_w2[h*DIM + d] * attn_w1[d*TH + t];
    Mg[t*PH + h] = f2bf(m);
    if (h == 0) {
        float cb = attn_b1[t];
        for (int d = 0; d < DIM; d++) cb += pos_b2[d] * attn_w1[d*TH + t];
        cbg[t] = cb;
    }
}

// per (b,j): q,k,v = x@w_qkv split; V f32 [b,j,d]; QW1 f32 [b,j,t]; KW1t bf16 [b,t,j]
__global__ void prep_qkv(const float* __restrict__ x, const float* __restrict__ w_qkv,
                         const float* __restrict__ attn_w1,
                         float* __restrict__ V, float* __restrict__ QW1, short* __restrict__ KW1t) {
    int bi = blockIdx.x;
    int b = bi >> 9, j = bi & (NN - 1);
    int tid = threadIdx.x;  // 256
    __shared__ float xs[DIM], qs[DIM], ks[DIM];
    if (tid < DIM) xs[tid] = x[bi*DIM + tid];
    __syncthreads();
    if (tid < 3*DIM) {
        float acc = 0.f;
        for (int e = 0; e < DIM; e++) acc += xs[e] * w_qkv[e*3*DIM + tid];
        if (tid < DIM) qs[tid] = acc;
        else if (tid < 2*DIM) ks[tid - DIM] = acc;
        else V[bi*DIM + (tid - 2*DIM)] = acc;
    }
    __syncthreads();
    float aq = 0.f, ak = 0.f;
    for (int d = 0; d < DIM; d++) {
        float w = attn_w1[d*TH + tid];
        aq += qs[d] * w; ak += ks[d] * w;
    }
    QW1[bi*TH + tid] = aq;
    KW1t[((size_t)(b*TH + tid))*NN + j] = f2bf(ak);
}

__launch_bounds__(512)
__global__ void ptl_main(const float* __restrict__ pos, const float* __restrict__ pos_w1,
                         const float* __restrict__ pos_b1, const float* __restrict__ pos_w2,
                         const float* __restrict__ pos_b2, const float* __restrict__ attn_w2,
                         const float* __restrict__ V, const float* __restrict__ QW1,
                         const short* __restrict__ KW1t, const short* __restrict__ Mg,
                         const float* __restrict__ cbg, float* __restrict__ out) {
    const int b = blockIdx.x >> 9, i = blockIdx.x & (NN - 1);
    const int tid = threadIdx.x;
    const int wv = tid >> 6, lane = tid & 63;
    const int lhi = lane >> 4, llo = lane & 15;

    __shared__ short Mlds[TH][PH + 8];     // stride 72 shorts = 144 B (16B-aligned rows)
    __shared__ float posl[NN][3];
    __shared__ float2 qw2[TH];             // {QW1[i,t]+cb[t], w2[t]}
    __shared__ float pw1l[3][PH], pb1l[PH];
    __shared__ float simbuf[NN], attnl[NN];
    __shared__ float red[64][9], redg[64][9];
    __shared__ float wmax[8], wsum[8];
    __shared__ float avl[64], gbarl[64];

    // ---- stage ----
    for (int idx = tid; idx < TH * 8; idx += 512) {       // 8 x 16B segs per row
        int t = idx >> 3, seg = idx & 7;
        *(uint4*)&Mlds[t][seg * 8] = *(const uint4*)&Mg[t * PH + seg * 8];
    }
    for (int idx = tid; idx < NN * 3; idx += 512)
        ((float*)posl)[idx] = pos[b * NN * 3 + idx];
    if (tid < TH) {
        float2 q2; q2.x = QW1[(b * NN + i) * TH + tid] + cbg[tid]; q2.y = attn_w2[tid];
        qw2[tid] = q2;
    }
    if (tid < 3 * PH) ((float*)pw1l)[tid] = pos_w1[tid];
    if (tid < PH) pb1l[tid] = pos_b1[tid];
    __syncthreads();

    const float pi0 = posl[i][0], pi1 = posl[i][1], pi2 = posl[i][2];

    // ---- MFMA phase: sim[j] for all 512 j ----
    for (int a = 0; a < 4; a++) {
        const int jt = wv + 8 * a;
        const int jA = jt * 16 + llo;                      // A-operand row (j)
        const float r0 = pi0 - posl[jA][0], r1 = pi1 - posl[jA][1], r2 = pi2 - posl[jA][2];
        bf16x8 afr[2];
        #pragma unroll
        for (int kk = 0; kk < 2; kk++) {
            #pragma unroll
            for (int e = 0; e < 8; e++) {
                int h = kk * 32 + lhi * 8 + e;
                float g = r0 * pw1l[0][h] + r1 * pw1l[1][h] + r2 * pw1l[2][h] + pb1l[h];
                afr[kk][e] = f2bf(fmaxf(g, 0.f));
            }
        }
        float simacc[4] = {0.f, 0.f, 0.f, 0.f};
        const int jc0 = jt * 16 + lhi * 4;                 // C rows for this lane
        const short* KWb = KW1t + ((size_t)b * TH) * NN + jc0;
        #pragma unroll 4
        for (int tt = 0; tt < 16; tt++) {
            const int t = tt * 16 + llo;
            uint2 kv = *(const uint2*)(KWb + (size_t)t * NN);
            bf16x8 bfr0 = *(const bf16x8*)&Mlds[t][0  + lhi * 8];
            bf16x8 bfr1 = *(const bf16x8*)&Mlds[t][32 + lhi * 8];
            f32x4 acc = {0.f, 0.f, 0.f, 0.f};
            acc = __builtin_amdgcn_mfma_f32_16x16x32_bf16(afr[0], bfr0, acc, 0, 0, 0);
            acc = __builtin_amdgcn_mfma_f32_16x16x32_bf16(afr[1], bfr1, acc, 0, 0, 0);
            const float2 qw = qw2[t];
            union { uint32_t u; float f; } k0, k1, k2, k3;
            k0.u = kv.x << 16; k1.u = kv.x & 0xffff0000u;
            k2.u = kv.y << 16; k3.u = kv.y & 0xffff0000u;
            simacc[0] += fmaxf(acc[0] + qw.x - k0.f, 0.f) * qw.y;
            simacc[1] += fmaxf(acc[1] + qw.x - k1.f, 0.f) * qw.y;
            simacc[2] += fmaxf(acc[2] + qw.x - k2.f, 0.f) * qw.y;
            simacc[3] += fmaxf(acc[3] + qw.x - k3.f, 0.f) * qw.y;
        }
        #pragma unroll
        for (int r = 0; r < 4; r++) {
            float v = simacc[r];
            v += __shfl_xor(v, 1); v += __shfl_xor(v, 2);
            v += __shfl_xor(v, 4); v += __shfl_xor(v, 8);
            if (llo == 0) simbuf[jc0 + r] = v;
        }
    }
    __syncthreads();

    // ---- softmax over j (one j per thread) ----
    float s = simbuf[tid];
    float mx = s;
    #pragma unroll
    for (int off = 1; off < 64; off <<= 1) mx = fmaxf(mx, __shfl_xor(mx, off));
    if (lane == 0) wmax[wv] = mx;
    __syncthreads();
    float bm = wmax[0];
    #pragma unroll
    for (int w = 1; w < 8; w++) bm = fmaxf(bm, wmax[w]);
    float p = __expf(s - bm);
    float ps = p;
    #pragma unroll
    for (int off = 1; off < 64; off <<= 1) ps += __shfl_xor(ps, off);
    if (lane == 0) wsum[wv] = ps;
    __syncthreads();
    float den = 0.f;
    #pragma unroll
    for (int w = 0; w < 8; w++) den += wsum[w];
    attnl[tid] = p / den;
    __syncthreads();

    // ---- aggregation: out = attn@V + (attn@G)@pos_w2 + pos_b2 ----
    const int d = tid & 63, grp = tid >> 6;
    float av = 0.f, ag = 0.f;
    for (int jj = 0; jj < 64; jj++) {
        const int j = grp * 64 + jj;
        const float aw = attnl[j];
        av += aw * V[(b * NN + j) * DIM + d];
        float q0 = pi0 - posl[j][0], q1 = pi1 - posl[j][1], q2 = pi2 - posl[j][2];
        float g = q0 * pw1l[0][d] + q1 * pw1l[1][d] + q2 * pw1l[2][d] + pb1l[d];
        ag += aw * fmaxf(g, 0.f);
    }
    red[d][grp] = av;
    redg[d][grp] = ag;
    __syncthreads();
    if (tid < 64) {
        float sv = 0.f, sg = 0.f;
        #pragma unroll
        for (int g2 = 0; g2 < 8; g2++) { sv += red[tid][g2]; sg += redg[tid][g2]; }
        avl[tid] = sv; gbarl[tid] = sg;
    }
    __syncthreads();
    if (tid < 64) {
        float o = avl[tid] + pos_b2[tid];
        for (int h = 0; h < PH; h++) o += gbarl[h] * pos_w2[h * DIM + tid];
        out[(size_t)blockIdx.x * DIM + tid] = o;
    }
}

extern "C" void kernel_launch(void* const* d_in, const int* in_sizes, int n_in,
                              void* d_out, int out_size, void* d_ws, size_t ws_size,
                              hipStream_t stream) {
    const float* x       = (const float*)d_in[0];
    const float* pos     = (const float*)d_in[1];
    const float* w_qkv   = (const float*)d_in[2];
    const float* pos_w1  = (const float*)d_in[3];
    const float* pos_b1  = (const float*)d_in[4];
    const float* pos_w2  = (const float*)d_in[5];
    const float* pos_b2  = (const float*)d_in[6];
    const float* attn_w1 = (const float*)d_in[7];
    const float* attn_b1 = (const float*)d_in[8];
    const float* attn_w2 = (const float*)d_in[9];
    // attn_b2 (d_in[10]) is softmax-invariant -> unused

    char* ws = (char*)d_ws;
    short* Mg   = (short*)(ws + 0);          //  32768 B
    float* cbg  = (float*)(ws + 32768);      //   1024 B
    float* Vw   = (float*)(ws + 33792);      // 524288 B
    float* QW1  = (float*)(ws + 558080);     // 2097152 B
    short* KW1t = (short*)(ws + 2655232);    // 1048576 B  (total ~3.6 MB)

    float* outp = (float*)d_out;

    prep_w  <<<64,     256, 0, stream>>>(pos_w2, attn_w1, pos_b2, attn_b1, Mg, cbg);
    prep_qkv<<<4 * NN, 256, 0, stream>>>(x, w_qkv, attn_w1, Vw, QW1, KW1t);
    ptl_main<<<4 * NN, 512, 0, stream>>>(pos, pos_w1, pos_b1, pos_w2, pos_b2,
                                         attn_w2, Vw, QW1, KW1t, Mg, cbg, outp);
}